// Round 2
// baseline (652.725 us; speedup 1.0000x reference)
//
#include <hip/hip_runtime.h>
#include <hip/hip_bf16.h>

// out[M,N] = x[M,K] @ W[N,K]^T + 2.0 * (x @ A[R,K]^T) @ B[N,R]^T
//          = x @ (W + 2.0 * B@A)^T
// M=16384, N=2048, K=2048, R=64.  fp32 in/out; bf16 MFMA internally.

typedef short short8 __attribute__((ext_vector_type(8)));
typedef float f32x4 __attribute__((ext_vector_type(4)));

#define BM 128
#define BN 128
#define BK 32

__device__ __forceinline__ unsigned short f2bf(float f) {
  unsigned u = __float_as_uint(f);
  u += 0x7fff + ((u >> 16) & 1);   // round-to-nearest-even
  return (unsigned short)(u >> 16);
}

// ---------------- pass 1: x fp32 -> bf16 ----------------
__global__ __launch_bounds__(256) void cvt_x_kernel(const float* __restrict__ x,
                                                    unsigned short* __restrict__ xb,
                                                    long long n) {
  long long idx = ((long long)blockIdx.x * 256 + threadIdx.x) * 8;
  long long stride = (long long)gridDim.x * 256 * 8;
  for (; idx < n; idx += stride) {
    float4 v0 = *(const float4*)(x + idx);
    float4 v1 = *(const float4*)(x + idx + 4);
    short8 o;
    o[0] = (short)f2bf(v0.x); o[1] = (short)f2bf(v0.y);
    o[2] = (short)f2bf(v0.z); o[3] = (short)f2bf(v0.w);
    o[4] = (short)f2bf(v1.x); o[5] = (short)f2bf(v1.y);
    o[6] = (short)f2bf(v1.z); o[7] = (short)f2bf(v1.w);
    *(short8*)(xb + idx) = o;
  }
}

// ---------------- pass 2: W_eff = bf16(W + scaling * B@A) ----------------
// Block handles 16 output rows (o) x all K columns. B rows staged in LDS.
__global__ __launch_bounds__(256) void weff_kernel(const float* __restrict__ W,
                                                   const float* __restrict__ Alora,
                                                   const float* __restrict__ Blora,
                                                   unsigned short* __restrict__ Weff,
                                                   int N, int K, int R, float scaling) {
  __shared__ float Bs[16][64];
  int t = threadIdx.x;
  int ob = blockIdx.x * 16;
  for (int j = t; j < 16 * 64; j += 256)
    Bs[j >> 6][j & 63] = Blora[(ob + (j >> 6)) * R + (j & 63)];
  __syncthreads();
  for (int ic = 0; ic < K; ic += 256) {
    int i = ic + t;
    float acc[16];
#pragma unroll
    for (int o = 0; o < 16; ++o) acc[o] = 0.f;
    for (int r = 0; r < 64; ++r) {
      float av = Alora[r * K + i];
#pragma unroll
      for (int o = 0; o < 16; ++o) acc[o] += Bs[o][r] * av;
    }
#pragma unroll
    for (int o = 0; o < 16; ++o) {
      float w = W[(size_t)(ob + o) * K + i];
      Weff[(size_t)(ob + o) * K + i] = f2bf(w + scaling * acc[o]);
    }
  }
}

// ---------------- pass 3: bf16 GEMM, C = Xb @ Wb^T (m97 structure) ----------------
#define GLOAD_LDS16(g, l)                                                        \
  __builtin_amdgcn_global_load_lds((const __attribute__((address_space(1))) void*)(g), \
                                   (__attribute__((address_space(3))) void*)(l), 16, 0, 0)

__global__ __launch_bounds__(256) void gemm_bt_kernel(const unsigned short* __restrict__ Xb,
                                                      const unsigned short* __restrict__ Wb,
                                                      float* __restrict__ out,
                                                      int M, int N, int K) {
  __shared__ __align__(16) unsigned short As[BM * BK];
  __shared__ __align__(16) unsigned short Bsh[BN * BK];

  int t = threadIdx.x;
  int lane = t & 63;
  int wave = t >> 6;
  int wr = wave >> 1, wc = wave & 1;
  int bm = blockIdx.y, bn = blockIdx.x;

  f32x4 acc[4][4];
  f32x4 z = {0.f, 0.f, 0.f, 0.f};
#pragma unroll
  for (int m = 0; m < 4; ++m)
#pragma unroll
    for (int n = 0; n < 4; ++n) acc[m][n] = z;

  // staging: thread t loads 8 bf16 (16B). issue0: row t/4, col (t%4)*8.
  // issue1: +64 rows.  LDS dest = t*16B (+4096B) = wave-uniform base + lane*16. OK.
  int srow = t >> 2;
  int scol = (t & 3) * 8;
  const unsigned short* Ag = Xb + (size_t)(bm * BM + srow) * K + scol;
  const unsigned short* Bg = Wb + (size_t)(bn * BN + srow) * K + scol;
  int ldsOff = t * 8;  // elements

  // MFMA fragment read offsets (elements): row stride BK
  int aoff = (wr * 64 + (lane & 15)) * BK + (lane >> 4) * 8;
  int boff = (wc * 64 + (lane & 15)) * BK + (lane >> 4) * 8;

  for (int k0 = 0; k0 < K; k0 += BK) {
    GLOAD_LDS16(Ag + k0,           As + ldsOff);
    GLOAD_LDS16(Ag + (size_t)64 * K + k0, As + ldsOff + 2048);
    GLOAD_LDS16(Bg + k0,           Bsh + ldsOff);
    GLOAD_LDS16(Bg + (size_t)64 * K + k0, Bsh + ldsOff + 2048);
    __syncthreads();

    short8 af[4], bf[4];
#pragma unroll
    for (int m = 0; m < 4; ++m) af[m] = *(const short8*)(As + aoff + m * 16 * BK);
#pragma unroll
    for (int n = 0; n < 4; ++n) bf[n] = *(const short8*)(Bsh + boff + n * 16 * BK);
#pragma unroll
    for (int m = 0; m < 4; ++m)
#pragma unroll
      for (int n = 0; n < 4; ++n)
        acc[m][n] = __builtin_amdgcn_mfma_f32_16x16x32_bf16(af[m], bf[n], acc[m][n], 0, 0, 0);
    __syncthreads();
  }

  // epilogue: C/D layout col = lane&15, row = (lane>>4)*4 + j  [m89/m91]
  int orow0 = bm * BM + wr * 64 + ((lane >> 4) << 2);
  int ocol0 = bn * BN + wc * 64 + (lane & 15);
#pragma unroll
  for (int m = 0; m < 4; ++m)
#pragma unroll
    for (int n = 0; n < 4; ++n) {
      size_t base = (size_t)(orow0 + m * 16) * N + (ocol0 + n * 16);
#pragma unroll
      for (int j = 0; j < 4; ++j) out[base + (size_t)j * N] = acc[m][n][j];
    }
}

extern "C" void kernel_launch(void* const* d_in, const int* in_sizes, int n_in,
                              void* d_out, int out_size, void* d_ws, size_t ws_size,
                              hipStream_t stream) {
  const float* x  = (const float*)d_in[0];
  const float* W  = (const float*)d_in[1];
  const float* Al = (const float*)d_in[2];
  const float* Bl = (const float*)d_in[3];
  float* out = (float*)d_out;

  const int K = 2048;
  const long long M = (long long)in_sizes[0] / K;  // 16384
  const int N = in_sizes[1] / K;                   // 2048
  const int R = in_sizes[2] / K;                   // 64

  unsigned short* xb   = (unsigned short*)d_ws;
  unsigned short* weff = xb + (size_t)M * K;       // needs (M*K + N*K)*2 = ~76 MB of ws

  cvt_x_kernel<<<2048, 256, 0, stream>>>(x, xb, (long long)M * K);
  weff_kernel<<<N / 16, 256, 0, stream>>>(W, Al, Bl, weff, N, K, R, 2.0f);
  gemm_bt_kernel<<<dim3(N / BN, (int)(M / BM)), 256, 0, stream>>>(xb, weff, out, (int)M, N, K);
}

// Round 3
// 446.341 us; speedup vs baseline: 1.4624x; 1.4624x over previous
//
#include <hip/hip_runtime.h>
#include <hip/hip_bf16.h>

// out[M,N] = x[M,K] @ W[N,K]^T + 2.0 * (x @ A[R,K]^T) @ B[N,R]^T
//          = x @ (W + 2.0 * B@A)^T
// M=16384, N=2048, K=2048, R=64.  fp32 in/out; bf16 MFMA internally.

typedef short short8 __attribute__((ext_vector_type(8)));
typedef float f32x4 __attribute__((ext_vector_type(4)));

#define BM 128
#define BN 128
#define BK 32

__device__ __forceinline__ unsigned short f2bf(float f) {
  unsigned u = __float_as_uint(f);
  u += 0x7fff + ((u >> 16) & 1);   // round-to-nearest-even
  return (unsigned short)(u >> 16);
}

// ---------------- pass 1: x fp32 -> bf16 ----------------
__global__ __launch_bounds__(256) void cvt_x_kernel(const float* __restrict__ x,
                                                    unsigned short* __restrict__ xb,
                                                    long long n) {
  long long idx = ((long long)blockIdx.x * 256 + threadIdx.x) * 8;
  long long stride = (long long)gridDim.x * 256 * 8;
  for (; idx < n; idx += stride) {
    float4 v0 = *(const float4*)(x + idx);
    float4 v1 = *(const float4*)(x + idx + 4);
    short8 o;
    o[0] = (short)f2bf(v0.x); o[1] = (short)f2bf(v0.y);
    o[2] = (short)f2bf(v0.z); o[3] = (short)f2bf(v0.w);
    o[4] = (short)f2bf(v1.x); o[5] = (short)f2bf(v1.y);
    o[6] = (short)f2bf(v1.z); o[7] = (short)f2bf(v1.w);
    *(short8*)(xb + idx) = o;
  }
}

// ---------------- pass 2: W_eff = bf16(W + scaling * B@A) ----------------
// R2 fix: one ic-chunk per block -> grid (K/256, N/16) = 1024 blocks
// (was 128 blocks serially walking 8 chunks @ 6% occupancy, 244 us).
__global__ __launch_bounds__(256) void weff_kernel(const float* __restrict__ W,
                                                   const float* __restrict__ Alora,
                                                   const float* __restrict__ Blora,
                                                   unsigned short* __restrict__ Weff,
                                                   int N, int K, int R, float scaling) {
  __shared__ float Bs[16][64];
  int t = threadIdx.x;
  int ob = blockIdx.y * 16;
  int i = blockIdx.x * 256 + t;
  for (int j = t; j < 16 * 64; j += 256)
    Bs[j >> 6][j & 63] = Blora[(ob + (j >> 6)) * R + (j & 63)];
  __syncthreads();
  float acc[16];
#pragma unroll
  for (int o = 0; o < 16; ++o) acc[o] = 0.f;
#pragma unroll 8
  for (int r = 0; r < 64; ++r) {
    float av = Alora[r * K + i];
#pragma unroll
    for (int o = 0; o < 16; ++o) acc[o] = fmaf(Bs[o][r], av, acc[o]);
  }
#pragma unroll
  for (int o = 0; o < 16; ++o) {
    float w = W[(size_t)(ob + o) * K + i];
    Weff[(size_t)(ob + o) * K + i] = f2bf(w + scaling * acc[o]);
  }
}

// ---------------- pass 3: bf16 GEMM, C = Xb @ Wb^T (m97 structure + T1 XCD swizzle) ----------------
#define GLOAD_LDS16(g, l)                                                        \
  __builtin_amdgcn_global_load_lds((const __attribute__((address_space(1))) void*)(g), \
                                   (__attribute__((address_space(3))) void*)(l), 16, 0, 0)

__global__ __launch_bounds__(256) void gemm_bt_kernel(const unsigned short* __restrict__ Xb,
                                                      const unsigned short* __restrict__ Wb,
                                                      float* __restrict__ out,
                                                      int M, int N, int K) {
  __shared__ __align__(16) unsigned short As[BM * BK];
  __shared__ __align__(16) unsigned short Bsh[BN * BK];

  int t = threadIdx.x;
  int lane = t & 63;
  int wave = t >> 6;
  int wr = wave >> 1, wc = wave & 1;

  // T1: XCD-aware bijective swizzle (nwg = gridDim.x, must be %8==0; 2048 is).
  // XCD x owns a contiguous chunk of bm-panels -> A-panel reused 16x in its L2.
  int nwg = gridDim.x;
  int cpx = nwg >> 3;
  int swz = (blockIdx.x & 7) * cpx + (blockIdx.x >> 3);
  int nbn = N / BN;
  int bm = swz / nbn, bn = swz % nbn;

  f32x4 acc[4][4];
  f32x4 z = {0.f, 0.f, 0.f, 0.f};
#pragma unroll
  for (int m = 0; m < 4; ++m)
#pragma unroll
    for (int n = 0; n < 4; ++n) acc[m][n] = z;

  // staging: thread t loads 8 bf16 (16B). issue0: row t/4, col (t%4)*8.
  // issue1: +64 rows.  LDS dest = t*16B (+4096B) = wave-uniform base + lane*16. OK.
  int srow = t >> 2;
  int scol = (t & 3) * 8;
  const unsigned short* Ag = Xb + (size_t)(bm * BM + srow) * K + scol;
  const unsigned short* Bg = Wb + (size_t)(bn * BN + srow) * K + scol;
  int ldsOff = t * 8;  // elements

  // MFMA fragment read offsets (elements): row stride BK
  int aoff = (wr * 64 + (lane & 15)) * BK + (lane >> 4) * 8;
  int boff = (wc * 64 + (lane & 15)) * BK + (lane >> 4) * 8;

  for (int k0 = 0; k0 < K; k0 += BK) {
    GLOAD_LDS16(Ag + k0,           As + ldsOff);
    GLOAD_LDS16(Ag + (size_t)64 * K + k0, As + ldsOff + 2048);
    GLOAD_LDS16(Bg + k0,           Bsh + ldsOff);
    GLOAD_LDS16(Bg + (size_t)64 * K + k0, Bsh + ldsOff + 2048);
    __syncthreads();

    short8 af[4], bf[4];
#pragma unroll
    for (int m = 0; m < 4; ++m) af[m] = *(const short8*)(As + aoff + m * 16 * BK);
#pragma unroll
    for (int n = 0; n < 4; ++n) bf[n] = *(const short8*)(Bsh + boff + n * 16 * BK);
#pragma unroll
    for (int m = 0; m < 4; ++m)
#pragma unroll
      for (int n = 0; n < 4; ++n)
        acc[m][n] = __builtin_amdgcn_mfma_f32_16x16x32_bf16(af[m], bf[n], acc[m][n], 0, 0, 0);
    __syncthreads();
  }

  // epilogue: C/D layout col = lane&15, row = (lane>>4)*4 + j  [m89/m91]
  int orow0 = bm * BM + wr * 64 + ((lane >> 4) << 2);
  int ocol0 = bn * BN + wc * 64 + (lane & 15);
#pragma unroll
  for (int m = 0; m < 4; ++m)
#pragma unroll
    for (int n = 0; n < 4; ++n) {
      size_t base = (size_t)(orow0 + m * 16) * N + (ocol0 + n * 16);
#pragma unroll
      for (int j = 0; j < 4; ++j) out[base + (size_t)j * N] = acc[m][n][j];
    }
}

extern "C" void kernel_launch(void* const* d_in, const int* in_sizes, int n_in,
                              void* d_out, int out_size, void* d_ws, size_t ws_size,
                              hipStream_t stream) {
  const float* x  = (const float*)d_in[0];
  const float* W  = (const float*)d_in[1];
  const float* Al = (const float*)d_in[2];
  const float* Bl = (const float*)d_in[3];
  float* out = (float*)d_out;

  const int K = 2048;
  const long long M = (long long)in_sizes[0] / K;  // 16384
  const int N = in_sizes[1] / K;                   // 2048
  const int R = in_sizes[2] / K;                   // 64

  unsigned short* xb   = (unsigned short*)d_ws;
  unsigned short* weff = xb + (size_t)M * K;       // needs (M*K + N*K)*2 = ~76 MB of ws

  cvt_x_kernel<<<2048, 256, 0, stream>>>(x, xb, (long long)M * K);
  weff_kernel<<<dim3(K / 256, N / 16), 256, 0, stream>>>(W, Al, Bl, weff, N, K, R, 2.0f);
  gemm_bt_kernel<<<(N / BN) * (int)(M / BM), 256, 0, stream>>>(xb, weff, out, (int)M, N, K);
}